// Round 1
// baseline (4822.545 us; speedup 1.0000x reference)
//
#include <hip/hip_runtime.h>
#include <math.h>

#define N 512
#define NITERS 100

// One workgroup (1024 threads) per batch matrix.
// Log-domain Sinkhorn with dual potentials:
//   u_i = lse_j(A_ij - v_j),  v_j = lse_i(A_ij - u_i),  A = X / 0.1
// A is constant; only u,v (512 floats each) change -> keep them in LDS,
// stream A from cache each pass. Final P = exp(A - u_i - v_j).
__global__ __launch_bounds__(1024, 1)
void sinkhorn_kernel(const float* __restrict__ X, float* __restrict__ P) {
    __shared__ float u_s[N];
    __shared__ float v_s[N];
    __shared__ float pm[1024];
    __shared__ float ps[1024];

    const int tid  = threadIdx.x;
    const int lane = tid & 63;
    const int wave = tid >> 6;            // 0..15

    const size_t base = (size_t)blockIdx.x * N * N;
    const float* __restrict__ A = X + base;
    float* __restrict__ out = P + base;

    if (tid < N) v_s[tid] = 0.0f;
    __syncthreads();

    const float SC = 10.0f;   // 1 / ENTROPY_REG

    for (int it = 0; it < NITERS; ++it) {
        // ---- row pass: u_r = lse_j(A[r][j]*SC - v[j]) ; wave per row ----
        #pragma unroll 1
        for (int r = wave; r < N; r += 16) {
            const float4* rowp = (const float4*)(A + (size_t)r * N);
            float4 a0 = rowp[lane];          // cols 4*lane .. 4*lane+3
            float4 a1 = rowp[lane + 64];     // cols 256+4*lane ..
            float4 vv0 = *(const float4*)(v_s + 4 * lane);
            float4 vv1 = *(const float4*)(v_s + 256 + 4 * lane);
            float x0 = fmaf(a0.x, SC, -vv0.x);
            float x1 = fmaf(a0.y, SC, -vv0.y);
            float x2 = fmaf(a0.z, SC, -vv0.z);
            float x3 = fmaf(a0.w, SC, -vv0.w);
            float x4 = fmaf(a1.x, SC, -vv1.x);
            float x5 = fmaf(a1.y, SC, -vv1.y);
            float x6 = fmaf(a1.z, SC, -vv1.z);
            float x7 = fmaf(a1.w, SC, -vv1.w);
            float m = fmaxf(fmaxf(fmaxf(x0, x1), fmaxf(x2, x3)),
                            fmaxf(fmaxf(x4, x5), fmaxf(x6, x7)));
            #pragma unroll
            for (int o = 32; o > 0; o >>= 1) m = fmaxf(m, __shfl_xor(m, o, 64));
            float s = __expf(x0 - m) + __expf(x1 - m) + __expf(x2 - m) + __expf(x3 - m)
                    + __expf(x4 - m) + __expf(x5 - m) + __expf(x6 - m) + __expf(x7 - m);
            #pragma unroll
            for (int o = 32; o > 0; o >>= 1) s += __shfl_xor(s, o, 64);
            if (lane == 0) u_s[r] = m + __logf(s);
        }
        __syncthreads();

        // ---- col pass: v_c = lse_i(A[i][c]*SC - u[i]) ----
        // thread t: column (t & 511), row-half (t >> 9). Online chunked lse.
        {
            const int c  = tid & (N - 1);
            const int i0 = (tid >> 9) * (N / 2);
            float m = -1.0e30f, s = 0.0f;
            #pragma unroll 1
            for (int i = i0; i < i0 + N / 2; i += 8) {
                float x[8];
                #pragma unroll
                for (int k = 0; k < 8; ++k)
                    x[k] = fmaf(A[(size_t)(i + k) * N + c], SC, -u_s[i + k]);
                float cm = x[0];
                #pragma unroll
                for (int k = 1; k < 8; ++k) cm = fmaxf(cm, x[k]);
                float mn = fmaxf(m, cm);
                float acc = s * __expf(m - mn);
                #pragma unroll
                for (int k = 0; k < 8; ++k) acc += __expf(x[k] - mn);
                m = mn; s = acc;
            }
            pm[tid] = m; ps[tid] = s;
        }
        __syncthreads();

        if (tid < N) {
            float m0 = pm[tid],       s0 = ps[tid];
            float m1 = pm[tid + 512], s1 = ps[tid + 512];
            float mn = fmaxf(m0, m1);
            float s  = s0 * __expf(m0 - mn) + s1 * __expf(m1 - mn);
            v_s[tid] = mn + __logf(s);
        }
        __syncthreads();
    }

    // ---- epilogue: P = exp(A*SC - u_r - v_c) ----
    #pragma unroll 1
    for (int r = wave; r < N; r += 16) {
        const float ur = u_s[r];
        const float4* rowp = (const float4*)(A + (size_t)r * N);
        float4* outp = (float4*)(out + (size_t)r * N);
        float4 a0 = rowp[lane];
        float4 a1 = rowp[lane + 64];
        float4 vv0 = *(const float4*)(v_s + 4 * lane);
        float4 vv1 = *(const float4*)(v_s + 256 + 4 * lane);
        float4 o0, o1;
        o0.x = __expf(fmaf(a0.x, SC, -vv0.x) - ur);
        o0.y = __expf(fmaf(a0.y, SC, -vv0.y) - ur);
        o0.z = __expf(fmaf(a0.z, SC, -vv0.z) - ur);
        o0.w = __expf(fmaf(a0.w, SC, -vv0.w) - ur);
        o1.x = __expf(fmaf(a1.x, SC, -vv1.x) - ur);
        o1.y = __expf(fmaf(a1.y, SC, -vv1.y) - ur);
        o1.z = __expf(fmaf(a1.z, SC, -vv1.z) - ur);
        o1.w = __expf(fmaf(a1.w, SC, -vv1.w) - ur);
        outp[lane]      = o0;
        outp[lane + 64] = o1;
    }
}

extern "C" void kernel_launch(void* const* d_in, const int* in_sizes, int n_in,
                              void* d_out, int out_size, void* d_ws, size_t ws_size,
                              hipStream_t stream) {
    const float* X = (const float*)d_in[0];
    float* P = (float*)d_out;
    const int batch = in_sizes[0] / (N * N);   // 128
    hipLaunchKernelGGL(sinkhorn_kernel, dim3(batch), dim3(1024), 0, stream, X, P);
}